// Round 1
// baseline (169.855 us; speedup 1.0000x reference)
//
#include <hip/hip_runtime.h>

#define NN 50000
#define NE 800000
#define NF 128
#define DIM 32
#define NG 500

// Kernel 1: y = x @ w_rel ; agg = x @ w_root + b_rel  (agg pre-init for scatter)
__global__ __launch_bounds__(256) void proj_kernel(
    const float* __restrict__ x, const float* __restrict__ w_rel,
    const float* __restrict__ w_root, const float* __restrict__ b_rel,
    float* __restrict__ y, float* __restrict__ agg)
{
    __shared__ float s_w[2 * NF * DIM];   // [0..4095]=w_rel, [4096..8191]=w_root
    __shared__ float s_x[4 * NF];
    int tid = threadIdx.x;
#pragma unroll
    for (int j = 0; j < 16; ++j) {
        s_w[tid + j * 256]        = w_rel[tid + j * 256];
        s_w[4096 + tid + j * 256] = w_root[tid + j * 256];
    }
    int row_base = blockIdx.x * 4;
    s_x[tid]       = x[row_base * NF + tid];
    s_x[tid + 256] = x[row_base * NF + tid + 256];
    __syncthreads();

    int r    = tid >> 6;        // 0..3 : row within block
    int lane = tid & 63;
    int col  = lane & 31;       // output column
    int sel  = lane >> 5;       // 0 -> w_rel/y, 1 -> w_root/agg
    int row  = row_base + r;

    const float* W  = s_w + sel * 4096;
    const float* xr = s_x + r * NF;
    float acc = sel ? b_rel[col] : 0.0f;
#pragma unroll 8
    for (int k = 0; k < NF; ++k)
        acc = fmaf(xr[k], W[k * DIM + col], acc);

    float* dstp = sel ? agg : y;
    dstp[row * DIM + col] = acc;
}

// Kernel 2: agg[dst] += w_e * y[src]   (32 threads per edge)
__global__ __launch_bounds__(256) void edge_kernel(
    const int* __restrict__ ei, const float* __restrict__ ew,
    const float* __restrict__ y, float* __restrict__ agg)
{
    int gtid = blockIdx.x * 256 + threadIdx.x;
    int e = gtid >> 5;
    int c = gtid & 31;
    if (e >= NE) return;
    int s   = ei[e];
    int d   = ei[NE + e];
    float w = ew[e];
    atomicAdd(&agg[d * DIM + c], y[s * DIM + c] * w);
}

// Kernel 3: pooled[batch[i]] += relu(agg[i])
__global__ __launch_bounds__(256) void pool_kernel(
    const float* __restrict__ agg, const int* __restrict__ batch,
    float* __restrict__ pooled)
{
    int gtid = blockIdx.x * 256 + threadIdx.x;
    int i = gtid >> 5;
    int c = gtid & 31;
    if (i >= NN) return;
    float v = agg[i * DIM + c];
    v = v > 0.0f ? v : 0.0f;
    atomicAdd(&pooled[batch[i] * DIM + c], v);
}

// Kernel 4: MLP head + log_softmax, one thread per graph
__global__ __launch_bounds__(512) void head_kernel(
    const float* __restrict__ pooled, const float* __restrict__ w_fc1,
    const float* __restrict__ b_fc1, const float* __restrict__ w_fc2,
    const float* __restrict__ b_fc2, float* __restrict__ out)
{
    __shared__ float s_fc1[DIM * DIM];
    __shared__ float s_b1[DIM];
    __shared__ float s_fc2[DIM * 2];
    __shared__ float s_b2[2];
    int tid = threadIdx.x;
    s_fc1[tid]       = w_fc1[tid];
    s_fc1[tid + 512] = w_fc1[tid + 512];
    if (tid < DIM * 2) s_fc2[tid] = w_fc2[tid];
    if (tid < DIM)     s_b1[tid]  = b_fc1[tid];
    if (tid < 2)       s_b2[tid]  = b_fc2[tid];
    __syncthreads();

    int g = tid;
    if (g >= NG) return;
    const float* p = pooled + g * DIM;
    float h2[DIM];
#pragma unroll
    for (int c = 0; c < DIM; ++c) {
        float a = s_b1[c];
#pragma unroll
        for (int k = 0; k < DIM; ++k)
            a = fmaf(p[k], s_fc1[k * DIM + c], a);
        h2[c] = a > 0.0f ? a : 0.0f;
    }
    float l0 = s_b2[0], l1 = s_b2[1];
#pragma unroll
    for (int c = 0; c < DIM; ++c) {
        l0 = fmaf(h2[c], s_fc2[c * 2 + 0], l0);
        l1 = fmaf(h2[c], s_fc2[c * 2 + 1], l1);
    }
    float m   = fmaxf(l0, l1);
    float lse = m + logf(expf(l0 - m) + expf(l1 - m));
    out[g * 2 + 0] = l0 - lse;
    out[g * 2 + 1] = l1 - lse;
}

extern "C" void kernel_launch(void* const* d_in, const int* in_sizes, int n_in,
                              void* d_out, int out_size, void* d_ws, size_t ws_size,
                              hipStream_t stream) {
    const float* x      = (const float*)d_in[0];
    const float* ew     = (const float*)d_in[1];
    const float* w_rel  = (const float*)d_in[2];
    const float* b_rel  = (const float*)d_in[3];
    const float* w_root = (const float*)d_in[4];
    const float* w_fc1  = (const float*)d_in[5];
    const float* b_fc1  = (const float*)d_in[6];
    const float* w_fc2  = (const float*)d_in[7];
    const float* b_fc2  = (const float*)d_in[8];
    const int*   ei     = (const int*)d_in[9];
    const int*   batch  = (const int*)d_in[10];
    float* out = (float*)d_out;

    char* ws = (char*)d_ws;
    float* y      = (float*)ws;                                  // 6.4 MB
    float* agg    = (float*)(ws + (size_t)NN * DIM * 4);         // 6.4 MB
    float* pooled = (float*)(ws + (size_t)2 * NN * DIM * 4);     // 64 KB

    hipMemsetAsync(pooled, 0, NG * DIM * sizeof(float), stream);

    proj_kernel<<<NN / 4, 256, 0, stream>>>(x, w_rel, w_root, b_rel, y, agg);
    edge_kernel<<<(NE * 32) / 256, 256, 0, stream>>>(ei, ew, y, agg);
    pool_kernel<<<(NN * 32 + 255) / 256, 256, 0, stream>>>(agg, batch, pooled);
    head_kernel<<<1, 512, 0, stream>>>(pooled, w_fc1, b_fc1, w_fc2, b_fc2, out);
}